// Round 9
// baseline (235.972 us; speedup 1.0000x reference)
//
#include <hip/hip_runtime.h>
#include <hip/hip_bf16.h>

#define B_ 8
#define S_ 2048
#define H_ 256
#define BS_ (B_*S_)

typedef __attribute__((ext_vector_type(8))) short bf16x8;
typedef __attribute__((ext_vector_type(4))) short bf16x4;
typedef __attribute__((ext_vector_type(4))) float f32x4;

static __device__ inline short f2bf(float f) {
  union { float f; unsigned int u; } a; a.f = f;
  unsigned int u = a.u;
  unsigned int r = (u + 0x7fffu + ((u >> 16) & 1u)) >> 16;
  return (short)r;
}

static __device__ inline float bf2f(short s) {
  union { float f; unsigned int u; } a;
  a.u = ((unsigned int)(unsigned short)s) << 16;
  return a.f;
}

static __device__ inline f32x4 mfma16(bf16x8 a, bf16x8 b, f32x4 c) {
  return __builtin_amdgcn_mfma_f32_16x16x32_bf16(a, b, c, 0, 0, 0);
}

// async global(16B/lane) -> LDS(wave-uniform base + lane*16)
static __device__ inline void gl_lds16(const short* g, short* l) {
  __builtin_amdgcn_global_load_lds(
      (const __attribute__((address_space(1))) void*)g,
      (__attribute__((address_space(3))) void*)l, 16, 0, 0);
}

// ---------------------------------------------------------------------------
// Kernel 0: fp32 -> bf16 conversion of Wq, Wk, Wv ONLY + zero den accumulator.
// ---------------------------------------------------------------------------
#define NW4 (H_ * H_ / 4)
#define NWTOT (3 * NW4)
#define NALLW (NWTOT + BS_ / 4)

__global__ __launch_bounds__(256) void cvt_bf16(
    const float* __restrict__ Wq, const float* __restrict__ Wk,
    const float* __restrict__ Wv,
    short* __restrict__ wqb, short* __restrict__ wkb, short* __restrict__ wvb,
    float* __restrict__ den)
{
  int stride = gridDim.x * blockDim.x;
  for (int i = blockIdx.x * blockDim.x + threadIdx.x; i < NALLW; i += stride) {
    if (i >= NWTOT) {                        // zero den (0xAA-poisoned ws)
      float4 z = {0.f, 0.f, 0.f, 0.f};
      *(float4*)(den + (size_t)(i - NWTOT) * 4) = z;
      continue;
    }
    int w = i >> 14;
    int off = i & (NW4 - 1);
    const float* src = (w == 0) ? Wq : (w == 1) ? Wk : Wv;
    short* dst = (w == 0) ? wqb : (w == 1) ? wkb : wvb;
    float4 v = *(const float4*)(src + off * 4);
    bf16x4 p;
    p[0] = f2bf(v.x); p[1] = f2bf(v.y); p[2] = f2bf(v.z); p[3] = f2bf(v.w);
    *(bf16x4*)(dst + off * 4) = p;
  }
}

// ---------------------------------------------------------------------------
// Kernel 1: Q/K row-major + V transposed [b][h][k]. grid (BS/64, 3), block 256.
// PIPELINED + FUSED x-convert (R6 version, passing twice).
// ---------------------------------------------------------------------------
__global__ __launch_bounds__(256) void qkv_proj(
    const float* __restrict__ x,
    const short* __restrict__ Wq, const float* __restrict__ bq,
    const short* __restrict__ Wk, const float* __restrict__ bk,
    const short* __restrict__ Wv, const float* __restrict__ bv,
    short* __restrict__ Qo, short* __restrict__ Ko, short* __restrict__ VTo)
{
  const int tid  = threadIdx.x;
  const int wave = tid >> 6;
  const int lane = tid & 63;
  const int quad = lane >> 4;
  const int l16  = lane & 15;
  const int y    = blockIdx.y;

  const short* W    = (y == 0) ? Wq : (y == 1) ? Wk : Wv;
  const float* bias = (y == 0) ? bq : (y == 1) ? bk : bv;
  const int sblk = blockIdx.x * 64;

  __shared__ short wbufA[16 * 512];
  __shared__ short xbufA[4 * 512];
  __shared__ short wbufB[16 * 512];
  __shared__ short xbufB[4 * 512];

  f32x4 zero = {0.f, 0.f, 0.f, 0.f};
  f32x4 acc[4][4];
#pragma unroll
  for (int i = 0; i < 4; i++)
#pragma unroll
    for (int j = 0; j < 4; j++) acc[i][j] = zero;

#define QKV_XLOAD(fa, fb, ch)                                             \
  {                                                                       \
    const float* xg = x + (size_t)(sblk + wave * 16 + l16) * H_ + (ch) * 32 + quad * 8; \
    fa = *(const float4*)xg;                                              \
    fb = *(const float4*)(xg + 4);                                        \
  }

#define QKV_XWRITE(xb_, fa, fb)                                           \
  {                                                                       \
    bf16x8 p;                                                             \
    p[0] = f2bf(fa.x); p[1] = f2bf(fa.y); p[2] = f2bf(fa.z); p[3] = f2bf(fa.w); \
    p[4] = f2bf(fb.x); p[5] = f2bf(fb.y); p[6] = f2bf(fb.z); p[7] = f2bf(fb.w); \
    *(bf16x8*)((xb_) + wave * 512 + lane * 8) = p;                        \
  }

#define QKV_STAGE_W(wb, ch)                                               \
  {                                                                       \
    _Pragma("unroll")                                                     \
    for (int i = 0; i < 4; i++) {                                         \
      int r = wave * 4 + i;                                               \
      gl_lds16(W + (r * 16 + l16) * H_ + (ch) * 32 + quad * 8, (wb) + r * 512); \
    }                                                                     \
  }

#define QKV_MFMA(wb, xb_)                                                 \
  {                                                                       \
    bf16x8 af[4];                                                         \
    _Pragma("unroll")                                                     \
    for (int st = 0; st < 4; st++)                                        \
      af[st] = *(const bf16x8*)((xb_) + st * 512 + lane * 8);             \
    _Pragma("unroll")                                                     \
    for (int i = 0; i < 4; i++) {                                         \
      bf16x8 bb = *(const bf16x8*)((wb) + (wave * 4 + i) * 512 + lane * 8); \
      _Pragma("unroll")                                                   \
      for (int st = 0; st < 4; st++)                                      \
        acc[st][i] = mfma16(af[st], bb, acc[st][i]);                      \
    }                                                                     \
  }

  float4 xa0, xb0, xa1, xb1;
  QKV_XLOAD(xa0, xb0, 0);
  QKV_STAGE_W(wbufA, 0);
  QKV_XWRITE(xbufA, xa0, xb0);
#pragma unroll
  for (int i2 = 0; i2 < 4; i2++) {
    __syncthreads();                         // publishes chunk 2*i2 (A)
    QKV_XLOAD(xa1, xb1, 2 * i2 + 1);         // x loads fly during MFMA(A)
    QKV_STAGE_W(wbufB, 2 * i2 + 1);          // W DMA flies during MFMA(A)
    QKV_MFMA(wbufA, xbufA);
    QKV_XWRITE(xbufB, xa1, xb1);             // lands before publishing barrier
    __syncthreads();                         // publishes chunk 2*i2+1 (B)
    if (i2 < 3) {
      QKV_XLOAD(xa0, xb0, 2 * i2 + 2);
      QKV_STAGE_W(wbufA, 2 * i2 + 2);
    }
    QKV_MFMA(wbufB, xbufB);
    if (i2 < 3) QKV_XWRITE(xbufA, xa0, xb0);
  }
#undef QKV_XLOAD
#undef QKV_XWRITE
#undef QKV_STAGE_W
#undef QKV_MFMA

  if (y < 2) {
    short* dst = (y == 0) ? Qo : Ko;
#pragma unroll
    for (int i = 0; i < 4; i++) {
      int col = (wave * 4 + i) * 16 + l16;
      float bvl = bias[col];
#pragma unroll
      for (int st = 0; st < 4; st++) {
#pragma unroll
        for (int r = 0; r < 4; r++) {
          int row = sblk + st * 16 + quad * 4 + r;
          dst[row * H_ + col] = f2bf(acc[st][i][r] + bvl);
        }
      }
    }
  } else {
#pragma unroll
    for (int i = 0; i < 4; i++) {
      int col = (wave * 4 + i) * 16 + l16;
      float bvl = bias[col];
#pragma unroll
      for (int st = 0; st < 4; st++) {
        int row0  = sblk + st * 16 + quad * 4;
        int b_idx = row0 >> 11;
        int k0    = row0 & (S_ - 1);
        bf16x4 pk;
#pragma unroll
        for (int r = 0; r < 4; r++) pk[r] = f2bf(acc[st][i][r] + bvl);
        *(bf16x4*)(VTo + (size_t)b_idx * H_ * S_ + (size_t)col * S_ + k0) = pk;
      }
    }
  }
}

// ---------------------------------------------------------------------------
// Kernel 2 (phase A): den[b][k] += sum_q exp(QK^T/256). R4/R8 scores with the
// P store DELETED (den-only; ~67 MB of writes removed). Structure unchanged:
// one 128q Q-tile x FOUR 128k K-tiles, K dbuf in registers, 1 barrier.
// grid 512 = 8b x 16qt x 4ktg.
// ---------------------------------------------------------------------------
__global__ __launch_bounds__(256, 2) void scores_den(
    const short* __restrict__ Q, const short* __restrict__ K,
    float* __restrict__ den)
{
  const int tid  = threadIdx.x;
  const int wave = tid >> 6;
  const int lane = tid & 63;
  const int quad = lane >> 4;
  const int l16  = lane & 15;
  const int ktg = blockIdx.x & 3;
  const int qt  = (blockIdx.x >> 2) & 15;
  const int b   = blockIdx.x >> 6;

  const short* Qb = Q + b * S_ * H_;
  const short* Kb = K + b * S_ * H_;
  const int qcol0 = qt * 128;

  __shared__ short qbuf[64 * 512];   // 64 KiB: full 128q x 256H tile

  bf16x8 kreg[2][2][8];
  {
    const short* kb = Kb + ((ktg * 4) * 128 + wave * 32 + l16) * H_ + quad * 8;
#pragma unroll
    for (int kf = 0; kf < 2; kf++)
#pragma unroll
      for (int ch = 0; ch < 8; ch++)
        kreg[0][kf][ch] = *(const bf16x8*)(kb + kf * 16 * H_ + ch * 32);
  }

#pragma unroll
  for (int i = 0; i < 16; i++) {
    int region = wave * 16 + i;
    int qf = region >> 3;
    int ch = region & 7;
    gl_lds16(Qb + (qcol0 + qf * 16 + l16) * H_ + ch * 32 + quad * 8,
             qbuf + region * 512);
  }
  __syncthreads();

#pragma unroll
  for (int t = 0; t < 4; t++) {
    if (t < 3) {
      const short* kb = Kb + ((ktg * 4 + t + 1) * 128 + wave * 32 + l16) * H_ + quad * 8;
#pragma unroll
      for (int kf = 0; kf < 2; kf++)
#pragma unroll
        for (int ch = 0; ch < 8; ch++)
          kreg[(t + 1) & 1][kf][ch] = *(const bf16x8*)(kb + kf * 16 * H_ + ch * 32);
    }

    f32x4 zero = {0.f, 0.f, 0.f, 0.f};
    f32x4 acc[2][8];
#pragma unroll
    for (int i = 0; i < 2; i++)
#pragma unroll
      for (int j = 0; j < 8; j++) acc[i][j] = zero;

#pragma unroll
    for (int ch = 0; ch < 8; ch++) {
#pragma unroll
      for (int qf = 0; qf < 8; qf++) {
        bf16x8 bq = *(const bf16x8*)(qbuf + (qf * 8 + ch) * 512 + lane * 8);
        acc[0][qf] = mfma16(kreg[t & 1][0][ch], bq, acc[0][qf]);
        acc[1][qf] = mfma16(kreg[t & 1][1][ch], bq, acc[1][qf]);
      }
    }

    const int krow0 = (ktg * 4 + t) * 128 + wave * 32;

    float rs[2][4] = {{0.f,0.f,0.f,0.f},{0.f,0.f,0.f,0.f}};
#pragma unroll
    for (int kf = 0; kf < 2; kf++) {
#pragma unroll
      for (int qf = 0; qf < 8; qf++) {
#pragma unroll
        for (int r = 0; r < 4; r++)
          rs[kf][r] += __expf(acc[kf][qf][r] * (1.0f / H_));
      }
    }

#pragma unroll
    for (int kf = 0; kf < 2; kf++) {
#pragma unroll
      for (int r = 0; r < 4; r++) {
        float v = rs[kf][r];
        v += __shfl_xor(v, 1, 64);
        v += __shfl_xor(v, 2, 64);
        v += __shfl_xor(v, 4, 64);
        v += __shfl_xor(v, 8, 64);
        if (l16 == 0)
          atomicAdd(&den[b * S_ + krow0 + kf * 16 + quad * 4 + r], v);
      }
    }
  }
}

// ---------------------------------------------------------------------------
// Kernel 3 (phase B): out = [exp(QK^T/256)/den] . V^T with QK^T RECOMPUTED —
// P never touches HBM (saves ~137 MB round-trip). Per block (b, qt=128q,
// hs=128h), grid 256 = 1 block/CU, bx = qt*16 + b*2 + hs (pv's proven
// XCD mapping: same-(b,hs) -> same XCD -> K/V L2 reuse).
// Per 128k chunk: QK^T (scores' exact frag math) -> exp * rcp(den) in
// C-layout (8 rcp/lane) -> P to LDS with scores' exact A-frag-linear store
// equation -> barrier -> PV (pv's exact read equation, pbuf instead of HBM).
// LDS 128 KiB: qbuf 64 + pbuf 32 + vbuf 32. V staged UNSCALED (vscale dead).
// ---------------------------------------------------------------------------
__global__ __launch_bounds__(256, 1) void pv_fused(
    const short* __restrict__ Q, const short* __restrict__ K,
    const short* __restrict__ VTs, const float* __restrict__ den,
    float* __restrict__ out)
{
  const int tid  = threadIdx.x;
  const int wave = tid >> 6;
  const int lane = tid & 63;
  const int quad = lane >> 4;
  const int l16  = lane & 15;
  const int bx = blockIdx.x;
  const int qt = bx >> 4;
  const int b  = (bx >> 1) & 7;
  const int hs = bx & 1;

  const short* Qb  = Q + b * S_ * H_;
  const short* Kb  = K + b * S_ * H_;
  const short* VTb = VTs + (size_t)b * H_ * S_ + (size_t)(hs * 128) * S_;
  const float* denb = den + b * S_;
  const int qcol0 = qt * 128;

  __shared__ short qbuf[64 * 512];   // 64 KiB: Q tile frag-linear
  __shared__ short pbuf[32 * 512];   // 32 KiB: P chunk 128q x 128k frag-linear
  __shared__ short vbuf[32 * 512];   // 32 KiB: V^T chunk 128h x 128k

  f32x4 zero = {0.f, 0.f, 0.f, 0.f};
  f32x4 accpv[2][8];
#pragma unroll
  for (int i = 0; i < 2; i++)
#pragma unroll
    for (int j = 0; j < 8; j++) accpv[i][j] = zero;

  // prologue: Q tile -> LDS frag-linear (scores' exact staging)
#pragma unroll
  for (int i = 0; i < 16; i++) {
    int region = wave * 16 + i;
    int qf = region >> 3;
    int ch = region & 7;
    gl_lds16(Qb + (qcol0 + qf * 16 + l16) * H_ + ch * 32 + quad * 8,
             qbuf + region * 512);
  }
  __syncthreads();

  const int quadA = quad >> 1;
  const int j0    = (quad & 1) * 4;

  for (int t = 0; t < 16; t++) {
    const int kc = t * 128;

    // K fragments -> registers (scores' exact A-frag loads); den float4s
    bf16x8 kreg[2][8];
    {
      const short* kb = Kb + (kc + wave * 32 + l16) * H_ + quad * 8;
#pragma unroll
      for (int kf = 0; kf < 2; kf++)
#pragma unroll
        for (int ch = 0; ch < 8; ch++)
          kreg[kf][ch] = *(const bf16x8*)(kb + kf * 16 * H_ + ch * 32);
    }
    float4 dv0 = *(const float4*)(denb + kc + wave * 32 + quad * 4);
    float4 dv1 = *(const float4*)(denb + kc + wave * 32 + 16 + quad * 4);

    // V chunk -> LDS (pv's exact staging; DMA covered by QK^T below)
#pragma unroll
    for (int i = 0; i < 8; i++) {
      int id = wave * 8 + i;
      int n  = id >> 2;
      int kw = id & 3;
      gl_lds16(VTb + (size_t)(n * 16 + l16) * S_ + kc + kw * 32 + quad * 8,
               vbuf + id * 512);
    }

    // QK^T + exp*(1/den) + P->LDS, kf-sequential (halves live acc VGPR)
#pragma unroll
    for (int kf = 0; kf < 2; kf++) {
      f32x4 a8[8];
#pragma unroll
      for (int j = 0; j < 8; j++) a8[j] = zero;
#pragma unroll
      for (int ch = 0; ch < 8; ch++) {
#pragma unroll
        for (int qf = 0; qf < 8; qf++) {
          bf16x8 bq = *(const bf16x8*)(qbuf + (qf * 8 + ch) * 512 + lane * 8);
          a8[qf] = mfma16(kreg[kf][ch], bq, a8[qf]);
        }
      }
      float rd[4];
      {
        float dd[4];
        if (kf == 0) { dd[0]=dv0.x; dd[1]=dv0.y; dd[2]=dv0.z; dd[3]=dv0.w; }
        else         { dd[0]=dv1.x; dd[1]=dv1.y; dd[2]=dv1.z; dd[3]=dv1.w; }
#pragma unroll
        for (int r = 0; r < 4; r++) {
          float rc = __builtin_amdgcn_rcpf(dd[r]);
          rc = rc * (2.0f - dd[r] * rc);
          rd[r] = rc;
        }
      }
#pragma unroll
      for (int qf = 0; qf < 8; qf++) {
        bf16x4 pk;
#pragma unroll
        for (int r = 0; r < 4; r++)
          pk[r] = f2bf(__expf(a8[qf][r] * (1.0f / H_)) * rd[r]);
        // scores' exact store equation; region (qf, kslot=wave)
        *(bf16x4*)(pbuf + (qf * 4 + wave) * 512 +
                   ((2 * kf + quadA) * 16 + l16) * 8 + j0) = pk;
      }
    }
    __syncthreads();   // drains pbuf ds_writes + vbuf DMA

    // PV (pv's exact inner loop; pbuf instead of HBM). wave covers 32 q.
#pragma unroll
    for (int qsub = 0; qsub < 2; qsub++) {
      const int qidx = wave * 2 + qsub;
      bf16x8 preg[4];
#pragma unroll
      for (int ks = 0; ks < 4; ks++)
        preg[ks] = *(const bf16x8*)(pbuf + (qidx * 4 + ks) * 512 + lane * 8);
#pragma unroll
      for (int ks = 0; ks < 4; ks++) {
#pragma unroll
        for (int n = 0; n < 8; n++) {
          bf16x8 vvb = *(const bf16x8*)(vbuf + (n * 4 + ks) * 512 + lane * 8);
          accpv[qsub][n] = mfma16(preg[ks], vvb, accpv[qsub][n]);
        }
      }
    }
    __syncthreads();   // all reads done before next chunk overwrites
  }

  // epilogue (pv's exact store equation)
#pragma unroll
  for (int qsub = 0; qsub < 2; qsub++) {
    const int q0 = qt * 128 + (wave * 2 + qsub) * 16;
#pragma unroll
    for (int n = 0; n < 8; n++) {
      int col = hs * 128 + n * 16 + l16;
#pragma unroll
      for (int r = 0; r < 4; r++) {
        int q = q0 + quad * 4 + r;
        out[((size_t)b * S_ + q) * H_ + col] = accpv[qsub][n][r];
      }
    }
  }
}

extern "C" void kernel_launch(void* const* d_in, const int* in_sizes, int n_in,
                              void* d_out, int out_size, void* d_ws, size_t ws_size,
                              hipStream_t stream) {
  const float* x  = (const float*)d_in[0];
  const float* Wq = (const float*)d_in[1];
  const float* bq = (const float*)d_in[2];
  const float* Wk = (const float*)d_in[3];
  const float* bk = (const float*)d_in[4];
  const float* Wv = (const float*)d_in[5];
  const float* bv = (const float*)d_in[6];

  short* xb  = (short*)d_ws;                       // layout kept stable
  short* wqb = xb  + (size_t)BS_ * H_;
  short* wkb = wqb + H_ * H_;
  short* wvb = wkb + H_ * H_;
  short* Qs  = wvb + H_ * H_;                      // 8 MiB
  short* Ks  = Qs  + (size_t)BS_ * H_;             // 8 MiB
  short* VT  = Ks  + (size_t)BS_ * H_;             // 8 MiB
  short* P   = VT  + (size_t)BS_ * H_;             // (unused now)
  float* den = (float*)(P + (size_t)B_ * S_ * S_); // 64 KiB
  float* outp = (float*)d_out;

  cvt_bf16<<<208, 256, 0, stream>>>(Wq, Wk, Wv, wqb, wkb, wvb, den);
  qkv_proj<<<dim3(BS_ / 64, 3), 256, 0, stream>>>(x, wqb, bq, wkb, bk, wvb, bv, Qs, Ks, VT);
  scores_den<<<512, 256, 0, stream>>>(Qs, Ks, den);
  pv_fused<<<256, 256, 0, stream>>>(Qs, Ks, VT, den, outp);
}

// Round 10
// 235.415 us; speedup vs baseline: 1.0024x; 1.0024x over previous
//
#include <hip/hip_runtime.h>
#include <hip/hip_bf16.h>

#define B_ 8
#define S_ 2048
#define H_ 256
#define BS_ (B_*S_)

typedef __attribute__((ext_vector_type(8))) short bf16x8;
typedef __attribute__((ext_vector_type(4))) short bf16x4;
typedef __attribute__((ext_vector_type(4))) float f32x4;

static __device__ inline short f2bf(float f) {
  union { float f; unsigned int u; } a; a.f = f;
  unsigned int u = a.u;
  unsigned int r = (u + 0x7fffu + ((u >> 16) & 1u)) >> 16;
  return (short)r;
}

static __device__ inline float bf2f(short s) {
  union { float f; unsigned int u; } a;
  a.u = ((unsigned int)(unsigned short)s) << 16;
  return a.f;
}

static __device__ inline f32x4 mfma16(bf16x8 a, bf16x8 b, f32x4 c) {
  return __builtin_amdgcn_mfma_f32_16x16x32_bf16(a, b, c, 0, 0, 0);
}

// async global(16B/lane) -> LDS(wave-uniform base + lane*16)
static __device__ inline void gl_lds16(const short* g, short* l) {
  __builtin_amdgcn_global_load_lds(
      (const __attribute__((address_space(1))) void*)g,
      (__attribute__((address_space(3))) void*)l, 16, 0, 0);
}

// ---------------------------------------------------------------------------
// Kernel 0: fp32 -> bf16 conversion of Wq, Wk, Wv ONLY + zero den accumulator.
// ---------------------------------------------------------------------------
#define NW4 (H_ * H_ / 4)
#define NWTOT (3 * NW4)
#define NALLW (NWTOT + BS_ / 4)

__global__ __launch_bounds__(256) void cvt_bf16(
    const float* __restrict__ Wq, const float* __restrict__ Wk,
    const float* __restrict__ Wv,
    short* __restrict__ wqb, short* __restrict__ wkb, short* __restrict__ wvb,
    float* __restrict__ den)
{
  int stride = gridDim.x * blockDim.x;
  for (int i = blockIdx.x * blockDim.x + threadIdx.x; i < NALLW; i += stride) {
    if (i >= NWTOT) {                        // zero den (0xAA-poisoned ws)
      float4 z = {0.f, 0.f, 0.f, 0.f};
      *(float4*)(den + (size_t)(i - NWTOT) * 4) = z;
      continue;
    }
    int w = i >> 14;
    int off = i & (NW4 - 1);
    const float* src = (w == 0) ? Wq : (w == 1) ? Wk : Wv;
    short* dst = (w == 0) ? wqb : (w == 1) ? wkb : wvb;
    float4 v = *(const float4*)(src + off * 4);
    bf16x4 p;
    p[0] = f2bf(v.x); p[1] = f2bf(v.y); p[2] = f2bf(v.z); p[3] = f2bf(v.w);
    *(bf16x4*)(dst + off * 4) = p;
  }
}

// ---------------------------------------------------------------------------
// Kernel 1: Q/K row-major + V transposed [b][h][k]. grid (BS/64, 3), block 256.
// PIPELINED + FUSED x-convert (passing in R8/R9, frozen).
// ---------------------------------------------------------------------------
__global__ __launch_bounds__(256) void qkv_proj(
    const float* __restrict__ x,
    const short* __restrict__ Wq, const float* __restrict__ bq,
    const short* __restrict__ Wk, const float* __restrict__ bk,
    const short* __restrict__ Wv, const float* __restrict__ bv,
    short* __restrict__ Qo, short* __restrict__ Ko, short* __restrict__ VTo)
{
  const int tid  = threadIdx.x;
  const int wave = tid >> 6;
  const int lane = tid & 63;
  const int quad = lane >> 4;
  const int l16  = lane & 15;
  const int y    = blockIdx.y;

  const short* W    = (y == 0) ? Wq : (y == 1) ? Wk : Wv;
  const float* bias = (y == 0) ? bq : (y == 1) ? bk : bv;
  const int sblk = blockIdx.x * 64;

  __shared__ short wbufA[16 * 512];
  __shared__ short xbufA[4 * 512];
  __shared__ short wbufB[16 * 512];
  __shared__ short xbufB[4 * 512];

  f32x4 zero = {0.f, 0.f, 0.f, 0.f};
  f32x4 acc[4][4];
#pragma unroll
  for (int i = 0; i < 4; i++)
#pragma unroll
    for (int j = 0; j < 4; j++) acc[i][j] = zero;

#define QKV_XLOAD(fa, fb, ch)                                             \
  {                                                                       \
    const float* xg = x + (size_t)(sblk + wave * 16 + l16) * H_ + (ch) * 32 + quad * 8; \
    fa = *(const float4*)xg;                                              \
    fb = *(const float4*)(xg + 4);                                        \
  }

#define QKV_XWRITE(xb_, fa, fb)                                           \
  {                                                                       \
    bf16x8 p;                                                             \
    p[0] = f2bf(fa.x); p[1] = f2bf(fa.y); p[2] = f2bf(fa.z); p[3] = f2bf(fa.w); \
    p[4] = f2bf(fb.x); p[5] = f2bf(fb.y); p[6] = f2bf(fb.z); p[7] = f2bf(fb.w); \
    *(bf16x8*)((xb_) + wave * 512 + lane * 8) = p;                        \
  }

#define QKV_STAGE_W(wb, ch)                                               \
  {                                                                       \
    _Pragma("unroll")                                                     \
    for (int i = 0; i < 4; i++) {                                         \
      int r = wave * 4 + i;                                               \
      gl_lds16(W + (r * 16 + l16) * H_ + (ch) * 32 + quad * 8, (wb) + r * 512); \
    }                                                                     \
  }

#define QKV_MFMA(wb, xb_)                                                 \
  {                                                                       \
    bf16x8 af[4];                                                         \
    _Pragma("unroll")                                                     \
    for (int st = 0; st < 4; st++)                                        \
      af[st] = *(const bf16x8*)((xb_) + st * 512 + lane * 8);             \
    _Pragma("unroll")                                                     \
    for (int i = 0; i < 4; i++) {                                         \
      bf16x8 bb = *(const bf16x8*)((wb) + (wave * 4 + i) * 512 + lane * 8); \
      _Pragma("unroll")                                                   \
      for (int st = 0; st < 4; st++)                                      \
        acc[st][i] = mfma16(af[st], bb, acc[st][i]);                      \
    }                                                                     \
  }

  float4 xa0, xb0, xa1, xb1;
  QKV_XLOAD(xa0, xb0, 0);
  QKV_STAGE_W(wbufA, 0);
  QKV_XWRITE(xbufA, xa0, xb0);
#pragma unroll
  for (int i2 = 0; i2 < 4; i2++) {
    __syncthreads();                         // publishes chunk 2*i2 (A)
    QKV_XLOAD(xa1, xb1, 2 * i2 + 1);         // x loads fly during MFMA(A)
    QKV_STAGE_W(wbufB, 2 * i2 + 1);          // W DMA flies during MFMA(A)
    QKV_MFMA(wbufA, xbufA);
    QKV_XWRITE(xbufB, xa1, xb1);             // lands before publishing barrier
    __syncthreads();                         // publishes chunk 2*i2+1 (B)
    if (i2 < 3) {
      QKV_XLOAD(xa0, xb0, 2 * i2 + 2);
      QKV_STAGE_W(wbufA, 2 * i2 + 2);
    }
    QKV_MFMA(wbufB, xbufB);
    if (i2 < 3) QKV_XWRITE(xbufA, xa0, xb0);
  }
#undef QKV_XLOAD
#undef QKV_XWRITE
#undef QKV_STAGE_W
#undef QKV_MFMA

  if (y < 2) {
    short* dst = (y == 0) ? Qo : Ko;
#pragma unroll
    for (int i = 0; i < 4; i++) {
      int col = (wave * 4 + i) * 16 + l16;
      float bvl = bias[col];
#pragma unroll
      for (int st = 0; st < 4; st++) {
#pragma unroll
        for (int r = 0; r < 4; r++) {
          int row = sblk + st * 16 + quad * 4 + r;
          dst[row * H_ + col] = f2bf(acc[st][i][r] + bvl);
        }
      }
    }
  } else {
#pragma unroll
    for (int i = 0; i < 4; i++) {
      int col = (wave * 4 + i) * 16 + l16;
      float bvl = bias[col];
#pragma unroll
      for (int st = 0; st < 4; st++) {
        int row0  = sblk + st * 16 + quad * 4;
        int b_idx = row0 >> 11;
        int k0    = row0 & (S_ - 1);
        bf16x4 pk;
#pragma unroll
        for (int r = 0; r < 4; r++) pk[r] = f2bf(acc[st][i][r] + bvl);
        *(bf16x4*)(VTo + (size_t)b_idx * H_ * S_ + (size_t)col * S_ + k0) = pk;
      }
    }
  }
}

// ---------------------------------------------------------------------------
// Kernel 2 (phase A): den[b][k] += sum_q exp(QK^T/256). R9-passing version,
// frozen. grid 512 = 8b x 16qt x 4ktg, 2 blocks/CU.
// ---------------------------------------------------------------------------
__global__ __launch_bounds__(256, 2) void scores_den(
    const short* __restrict__ Q, const short* __restrict__ K,
    float* __restrict__ den)
{
  const int tid  = threadIdx.x;
  const int wave = tid >> 6;
  const int lane = tid & 63;
  const int quad = lane >> 4;
  const int l16  = lane & 15;
  const int ktg = blockIdx.x & 3;
  const int qt  = (blockIdx.x >> 2) & 15;
  const int b   = blockIdx.x >> 6;

  const short* Qb = Q + b * S_ * H_;
  const short* Kb = K + b * S_ * H_;
  const int qcol0 = qt * 128;

  __shared__ short qbuf[64 * 512];   // 64 KiB

  bf16x8 kreg[2][2][8];
  {
    const short* kb = Kb + ((ktg * 4) * 128 + wave * 32 + l16) * H_ + quad * 8;
#pragma unroll
    for (int kf = 0; kf < 2; kf++)
#pragma unroll
      for (int ch = 0; ch < 8; ch++)
        kreg[0][kf][ch] = *(const bf16x8*)(kb + kf * 16 * H_ + ch * 32);
  }

#pragma unroll
  for (int i = 0; i < 16; i++) {
    int region = wave * 16 + i;
    int qf = region >> 3;
    int ch = region & 7;
    gl_lds16(Qb + (qcol0 + qf * 16 + l16) * H_ + ch * 32 + quad * 8,
             qbuf + region * 512);
  }
  __syncthreads();

#pragma unroll
  for (int t = 0; t < 4; t++) {
    if (t < 3) {
      const short* kb = Kb + ((ktg * 4 + t + 1) * 128 + wave * 32 + l16) * H_ + quad * 8;
#pragma unroll
      for (int kf = 0; kf < 2; kf++)
#pragma unroll
        for (int ch = 0; ch < 8; ch++)
          kreg[(t + 1) & 1][kf][ch] = *(const bf16x8*)(kb + kf * 16 * H_ + ch * 32);
    }

    f32x4 zero = {0.f, 0.f, 0.f, 0.f};
    f32x4 acc[2][8];
#pragma unroll
    for (int i = 0; i < 2; i++)
#pragma unroll
      for (int j = 0; j < 8; j++) acc[i][j] = zero;

#pragma unroll
    for (int ch = 0; ch < 8; ch++) {
#pragma unroll
      for (int qf = 0; qf < 8; qf++) {
        bf16x8 bq = *(const bf16x8*)(qbuf + (qf * 8 + ch) * 512 + lane * 8);
        acc[0][qf] = mfma16(kreg[t & 1][0][ch], bq, acc[0][qf]);
        acc[1][qf] = mfma16(kreg[t & 1][1][ch], bq, acc[1][qf]);
      }
    }

    const int krow0 = (ktg * 4 + t) * 128 + wave * 32;

    float rs[2][4] = {{0.f,0.f,0.f,0.f},{0.f,0.f,0.f,0.f}};
#pragma unroll
    for (int kf = 0; kf < 2; kf++) {
#pragma unroll
      for (int qf = 0; qf < 8; qf++) {
#pragma unroll
        for (int r = 0; r < 4; r++)
          rs[kf][r] += __expf(acc[kf][qf][r] * (1.0f / H_));
      }
    }

#pragma unroll
    for (int kf = 0; kf < 2; kf++) {
#pragma unroll
      for (int r = 0; r < 4; r++) {
        float v = rs[kf][r];
        v += __shfl_xor(v, 1, 64);
        v += __shfl_xor(v, 2, 64);
        v += __shfl_xor(v, 4, 64);
        v += __shfl_xor(v, 8, 64);
        if (l16 == 0)
          atomicAdd(&den[b * S_ + krow0 + kf * 16 + quad * 4 + r], v);
      }
    }
  }
}

// ---------------------------------------------------------------------------
// Kernel 3 (phase B) v2: out = [exp(QK^T/256)/den] . V^T, QK^T recomputed.
// R9 FIX: tile shrunk 128q -> 64q so LDS = 32(q)+16(p)+32(v) = 80 KiB ->
// 2 blocks/CU (R9's 128 KiB forced 1 wave/SIMD = zero latency hiding, 115us).
// + kreg/den register double-buffer prefetch (R4's proven pattern), issued
// before the barrier so it flies under barrier+PV.
// grid 512 = 8b x 32qt x 2hs, bx = qt*16 + b*2 + hs (pv's XCD mapping).
// All P-redistribution index equations verbatim from the R9-PASSING kernel.
// ---------------------------------------------------------------------------
__global__ __launch_bounds__(256, 2) void pv_fused(
    const short* __restrict__ Q, const short* __restrict__ K,
    const short* __restrict__ VTs, const float* __restrict__ den,
    float* __restrict__ out)
{
  const int tid  = threadIdx.x;
  const int wave = tid >> 6;
  const int lane = tid & 63;
  const int quad = lane >> 4;
  const int l16  = lane & 15;
  const int bx = blockIdx.x;
  const int qt = bx >> 4;          // 0..31 (64q each)
  const int b  = (bx >> 1) & 7;
  const int hs = bx & 1;

  const short* Qb  = Q + b * S_ * H_;
  const short* Kb  = K + b * S_ * H_;
  const short* VTb = VTs + (size_t)b * H_ * S_ + (size_t)(hs * 128) * S_;
  const float* denb = den + b * S_;
  const int qcol0 = qt * 64;

  __shared__ short qbuf[32 * 512];   // 32 KiB: 64q x 256H frag-linear
  __shared__ short pbuf[16 * 512];   // 16 KiB: 64q x 128k frag-linear
  __shared__ short vbuf[32 * 512];   // 32 KiB: 128h x 128k

  f32x4 zero = {0.f, 0.f, 0.f, 0.f};
  f32x4 accpv[8];
#pragma unroll
  for (int i = 0; i < 8; i++) accpv[i] = zero;

  // Q tile -> LDS frag-linear (region = qf*8 + ch, qf<4), 8 regions/wave
#pragma unroll
  for (int i = 0; i < 8; i++) {
    int region = wave * 8 + i;
    int qf = region >> 3;
    int ch = region & 7;
    gl_lds16(Qb + (qcol0 + qf * 16 + l16) * H_ + ch * 32 + quad * 8,
             qbuf + region * 512);
  }

  // prologue: kreg/den for chunk 0 -> A buffers (fly during Q staging drain)
  bf16x8 kregA[2][8], kregB[2][8];
  float4 dvA0, dvA1, dvB0, dvB1;
  {
    const short* kb = Kb + (wave * 32 + l16) * H_ + quad * 8;
#pragma unroll
    for (int kf = 0; kf < 2; kf++)
#pragma unroll
      for (int ch = 0; ch < 8; ch++)
        kregA[kf][ch] = *(const bf16x8*)(kb + kf * 16 * H_ + ch * 32);
    dvA0 = *(const float4*)(denb + wave * 32 + quad * 4);
    dvA1 = *(const float4*)(denb + wave * 32 + 16 + quad * 4);
  }
  __syncthreads();   // Q ready

  const int quadA = quad >> 1;
  const int j0    = (quad & 1) * 4;

  // one fused chunk: stage V, QK^T+exp/den -> pbuf, prefetch next kreg/den,
  // barrier, PV, barrier.  (kr,d0,d1) = this chunk's regs; (nkr,nd0,nd1) =
  // prefetch destination (other parity).
#define FCHUNK(kr, d0, d1, nkr, nd0, nd1, t, DOPF)                          \
  {                                                                         \
    const int kc = (t) * 128;                                               \
    _Pragma("unroll")                                                       \
    for (int i = 0; i < 8; i++) {                                           \
      int id = wave * 8 + i;                                                \
      int n  = id >> 2;                                                     \
      int kw = id & 3;                                                      \
      gl_lds16(VTb + (size_t)(n * 16 + l16) * S_ + kc + kw * 32 + quad * 8, \
               vbuf + id * 512);                                            \
    }                                                                       \
    _Pragma("unroll")                                                       \
    for (int kf = 0; kf < 2; kf++) {                                        \
      f32x4 a8[4];                                                          \
      _Pragma("unroll")                                                     \
      for (int j = 0; j < 4; j++) a8[j] = zero;                             \
      _Pragma("unroll")                                                     \
      for (int ch = 0; ch < 8; ch++) {                                      \
        _Pragma("unroll")                                                   \
        for (int qf = 0; qf < 4; qf++) {                                    \
          bf16x8 bq = *(const bf16x8*)(qbuf + (qf * 8 + ch) * 512 + lane * 8); \
          a8[qf] = mfma16(kr[kf][ch], bq, a8[qf]);                          \
        }                                                                   \
      }                                                                     \
      float rd[4];                                                          \
      {                                                                     \
        float dd[4];                                                        \
        if (kf == 0) { dd[0]=d0.x; dd[1]=d0.y; dd[2]=d0.z; dd[3]=d0.w; }    \
        else         { dd[0]=d1.x; dd[1]=d1.y; dd[2]=d1.z; dd[3]=d1.w; }    \
        _Pragma("unroll")                                                   \
        for (int r = 0; r < 4; r++) {                                       \
          float rc = __builtin_amdgcn_rcpf(dd[r]);                          \
          rc = rc * (2.0f - dd[r] * rc);                                    \
          rd[r] = rc;                                                       \
        }                                                                   \
      }                                                                     \
      _Pragma("unroll")                                                     \
      for (int qf = 0; qf < 4; qf++) {                                      \
        bf16x4 pk;                                                          \
        _Pragma("unroll")                                                   \
        for (int r = 0; r < 4; r++)                                         \
          pk[r] = f2bf(__expf(a8[qf][r] * (1.0f / H_)) * rd[r]);            \
        *(bf16x4*)(pbuf + (qf * 4 + wave) * 512 +                           \
                   ((2 * kf + quadA) * 16 + l16) * 8 + j0) = pk;            \
      }                                                                     \
    }                                                                       \
    if (DOPF) {                                                             \
      const short* kb = Kb + ((t + 1) * 128 + wave * 32 + l16) * H_ + quad * 8; \
      _Pragma("unroll")                                                     \
      for (int kf = 0; kf < 2; kf++)                                        \
        _Pragma("unroll")                                                   \
        for (int ch = 0; ch < 8; ch++)                                      \
          nkr[kf][ch] = *(const bf16x8*)(kb + kf * 16 * H_ + ch * 32);      \
      nd0 = *(const float4*)(denb + (t + 1) * 128 + wave * 32 + quad * 4);  \
      nd1 = *(const float4*)(denb + (t + 1) * 128 + wave * 32 + 16 + quad * 4); \
    }                                                                       \
    __syncthreads();   /* pbuf writes + vbuf DMA drained */                 \
    bf16x8 preg[4];                                                         \
    _Pragma("unroll")                                                       \
    for (int ks = 0; ks < 4; ks++)                                          \
      preg[ks] = *(const bf16x8*)(pbuf + (wave * 4 + ks) * 512 + lane * 8); \
    _Pragma("unroll")                                                       \
    for (int ks = 0; ks < 4; ks++) {                                        \
      _Pragma("unroll")                                                     \
      for (int n = 0; n < 8; n++) {                                         \
        bf16x8 vvb = *(const bf16x8*)(vbuf + (n * 4 + ks) * 512 + lane * 8); \
        accpv[n] = mfma16(preg[ks], vvb, accpv[n]);                         \
      }                                                                     \
    }                                                                       \
    __syncthreads();   /* reads done before next chunk overwrites */        \
  }

  for (int i2 = 0; i2 < 8; i2++) {
    FCHUNK(kregA, dvA0, dvA1, kregB, dvB0, dvB1, 2 * i2, 1);
    FCHUNK(kregB, dvB0, dvB1, kregA, dvA0, dvA1, 2 * i2 + 1, (i2 < 7));
  }
#undef FCHUNK

  // epilogue (pv's proven store equation; qidx = wave)
  const int q0 = qt * 64 + wave * 16;
#pragma unroll
  for (int n = 0; n < 8; n++) {
    int col = hs * 128 + n * 16 + l16;
#pragma unroll
    for (int r = 0; r < 4; r++) {
      int q = q0 + quad * 4 + r;
      out[((size_t)b * S_ + q) * H_ + col] = accpv[n][r];
    }
  }
}

extern "C" void kernel_launch(void* const* d_in, const int* in_sizes, int n_in,
                              void* d_out, int out_size, void* d_ws, size_t ws_size,
                              hipStream_t stream) {
  const float* x  = (const float*)d_in[0];
  const float* Wq = (const float*)d_in[1];
  const float* bq = (const float*)d_in[2];
  const float* Wk = (const float*)d_in[3];
  const float* bk = (const float*)d_in[4];
  const float* Wv = (const float*)d_in[5];
  const float* bv = (const float*)d_in[6];

  short* xb  = (short*)d_ws;                       // layout kept stable
  short* wqb = xb  + (size_t)BS_ * H_;
  short* wkb = wqb + H_ * H_;
  short* wvb = wkb + H_ * H_;
  short* Qs  = wvb + H_ * H_;                      // 8 MiB
  short* Ks  = Qs  + (size_t)BS_ * H_;             // 8 MiB
  short* VT  = Ks  + (size_t)BS_ * H_;             // 8 MiB
  short* P   = VT  + (size_t)BS_ * H_;             // (unused now)
  float* den = (float*)(P + (size_t)B_ * S_ * S_); // 64 KiB
  float* outp = (float*)d_out;

  cvt_bf16<<<208, 256, 0, stream>>>(Wq, Wk, Wv, wqb, wkb, wvb, den);
  qkv_proj<<<dim3(BS_ / 64, 3), 256, 0, stream>>>(x, wqb, bq, wkb, bk, wvb, bv, Qs, Ks, VT);
  scores_den<<<512, 256, 0, stream>>>(Qs, Ks, den);
  pv_fused<<<512, 256, 0, stream>>>(Qs, Ks, VT, den, outp);
}

// Round 11
// 184.684 us; speedup vs baseline: 1.2777x; 1.2747x over previous
//
#include <hip/hip_runtime.h>
#include <hip/hip_bf16.h>

#define B_ 8
#define S_ 2048
#define H_ 256
#define BS_ (B_*S_)

typedef __attribute__((ext_vector_type(8))) short bf16x8;
typedef __attribute__((ext_vector_type(4))) short bf16x4;
typedef __attribute__((ext_vector_type(4))) float f32x4;

static __device__ inline short f2bf(float f) {
  union { float f; unsigned int u; } a; a.f = f;
  unsigned int u = a.u;
  unsigned int r = (u + 0x7fffu + ((u >> 16) & 1u)) >> 16;
  return (short)r;
}

static __device__ inline float bf2f(short s) {
  union { float f; unsigned int u; } a;
  a.u = ((unsigned int)(unsigned short)s) << 16;
  return a.f;
}

static __device__ inline f32x4 mfma16(bf16x8 a, bf16x8 b, f32x4 c) {
  return __builtin_amdgcn_mfma_f32_16x16x32_bf16(a, b, c, 0, 0, 0);
}

// async global(16B/lane) -> LDS(wave-uniform base + lane*16)
static __device__ inline void gl_lds16(const short* g, short* l) {
  __builtin_amdgcn_global_load_lds(
      (const __attribute__((address_space(1))) void*)g,
      (__attribute__((address_space(3))) void*)l, 16, 0, 0);
}

// ---------------------------------------------------------------------------
// Kernel 0: fp32 -> bf16 conversion of x, Wq, Wk, Wv + zero den accumulator.
// ---------------------------------------------------------------------------
#define NX4 (BS_ * H_ / 4)
#define NW4 (H_ * H_ / 4)
#define NTOT4 (NX4 + 3 * NW4)
#define NALL4 (NTOT4 + BS_ / 4)

__global__ __launch_bounds__(256) void cvt_bf16(
    const float* __restrict__ x,
    const float* __restrict__ Wq, const float* __restrict__ Wk,
    const float* __restrict__ Wv,
    short* __restrict__ xb, short* __restrict__ wqb,
    short* __restrict__ wkb, short* __restrict__ wvb,
    float* __restrict__ den)
{
  int stride = gridDim.x * blockDim.x;
  for (int i = blockIdx.x * blockDim.x + threadIdx.x; i < NALL4; i += stride) {
    if (i >= NTOT4) {                        // zero den (0xAA-poisoned ws)
      float4 z = {0.f, 0.f, 0.f, 0.f};
      *(float4*)(den + (size_t)(i - NTOT4) * 4) = z;
      continue;
    }
    const float* src; short* dst; int off;
    if (i < NX4) { src = x; dst = xb; off = i; }
    else {
      int j = i - NX4;
      int w = j >> 14;
      off = j & (NW4 - 1);
      src = (w == 0) ? Wq : (w == 1) ? Wk : Wv;
      dst = (w == 0) ? wqb : (w == 1) ? wkb : wvb;
    }
    float4 v = *(const float4*)(src + off * 4);
    bf16x4 p;
    p[0] = f2bf(v.x); p[1] = f2bf(v.y); p[2] = f2bf(v.z); p[3] = f2bf(v.w);
    *(bf16x4*)(dst + off * 4) = p;
  }
}

// ---------------------------------------------------------------------------
// Kernel 1: Q/K row-major + V transposed [b][h][k]. grid (BS/64, 3), block 256.
// LDS-staged; wave = 64s x 64c.  (R4-measured version.)
// ---------------------------------------------------------------------------
__global__ __launch_bounds__(256) void qkv_proj(
    const short* __restrict__ x,
    const short* __restrict__ Wq, const float* __restrict__ bq,
    const short* __restrict__ Wk, const float* __restrict__ bk,
    const short* __restrict__ Wv, const float* __restrict__ bv,
    short* __restrict__ Qo, short* __restrict__ Ko, short* __restrict__ VTo)
{
  const int tid  = threadIdx.x;
  const int wave = tid >> 6;
  const int lane = tid & 63;
  const int quad = lane >> 4;
  const int l16  = lane & 15;
  const int y    = blockIdx.y;

  const short* W    = (y == 0) ? Wq : (y == 1) ? Wk : Wv;
  const float* bias = (y == 0) ? bq : (y == 1) ? bk : bv;
  const int sblk = blockIdx.x * 64;

  __shared__ short wbuf[16 * 512];
  __shared__ short xbuf[4 * 512];

  f32x4 zero = {0.f, 0.f, 0.f, 0.f};
  f32x4 acc[4][4];
#pragma unroll
  for (int i = 0; i < 4; i++)
#pragma unroll
    for (int j = 0; j < 4; j++) acc[i][j] = zero;

  for (int ch = 0; ch < 8; ch++) {
#pragma unroll
    for (int i = 0; i < 4; i++) {
      int r = wave * 4 + i;
      gl_lds16(W + (r * 16 + l16) * H_ + ch * 32 + quad * 8, wbuf + r * 512);
    }
    gl_lds16(x + (sblk + wave * 16 + l16) * H_ + ch * 32 + quad * 8,
             xbuf + wave * 512);
    __syncthreads();
    bf16x8 af[4];
#pragma unroll
    for (int st = 0; st < 4; st++)
      af[st] = *(const bf16x8*)(xbuf + st * 512 + lane * 8);
#pragma unroll
    for (int i = 0; i < 4; i++) {
      bf16x8 bb = *(const bf16x8*)(wbuf + (wave * 4 + i) * 512 + lane * 8);
#pragma unroll
      for (int st = 0; st < 4; st++)
        acc[st][i] = mfma16(af[st], bb, acc[st][i]);
    }
    __syncthreads();
  }

  if (y < 2) {
    short* dst = (y == 0) ? Qo : Ko;
#pragma unroll
    for (int i = 0; i < 4; i++) {
      int col = (wave * 4 + i) * 16 + l16;
      float bvl = bias[col];
#pragma unroll
      for (int st = 0; st < 4; st++) {
#pragma unroll
        for (int r = 0; r < 4; r++) {
          int row = sblk + st * 16 + quad * 4 + r;
          dst[row * H_ + col] = f2bf(acc[st][i][r] + bvl);
        }
      }
    }
  } else {
#pragma unroll
    for (int i = 0; i < 4; i++) {
      int col = (wave * 4 + i) * 16 + l16;
      float bvl = bias[col];
#pragma unroll
      for (int st = 0; st < 4; st++) {
        int row0  = sblk + st * 16 + quad * 4;
        int b_idx = row0 >> 11;
        int k0    = row0 & (S_ - 1);
        bf16x4 pk;
#pragma unroll
        for (int r = 0; r < 4; r++) pk[r] = f2bf(acc[st][i][r] + bvl);
        *(bf16x4*)(VTo + (size_t)b_idx * H_ * S_ + (size_t)col * S_ + k0) = pk;
      }
    }
  }
}

// ---------------------------------------------------------------------------
// Kernel 2: P = exp(QK^T/256) in A-FRAGMENT-LINEARIZED layout; den += rowsums.
// R4-measured version (44.2us): one 128q Q-tile (LDS, staged once) x FOUR
// 128k K-tiles, K double-buffered in registers, no barrier in kt loop.
// grid 512 = 8b x 16qt x 4ktg, 2 blocks/CU, one generation.
// ---------------------------------------------------------------------------
__global__ __launch_bounds__(256, 2) void scores(
    const short* __restrict__ Q, const short* __restrict__ K,
    short* __restrict__ Pf, float* __restrict__ den)
{
  const int tid  = threadIdx.x;
  const int wave = tid >> 6;
  const int lane = tid & 63;
  const int quad = lane >> 4;
  const int l16  = lane & 15;
  const int ktg = blockIdx.x & 3;           // 4 consecutive kt tiles
  const int qt  = (blockIdx.x >> 2) & 15;
  const int b   = blockIdx.x >> 6;

  const short* Qb = Q + b * S_ * H_;
  const short* Kb = K + b * S_ * H_;
  const int qcol0 = qt * 128;

  __shared__ short qbuf[64 * 512];   // 64 KiB: full 128q x 256H tile

  // prologue: K tile t=0 -> registers (A-frag layout direct from row-major K)
  bf16x8 kreg[2][2][8];
  {
    const short* kb = Kb + ((ktg * 4) * 128 + wave * 32 + l16) * H_ + quad * 8;
#pragma unroll
    for (int kf = 0; kf < 2; kf++)
#pragma unroll
      for (int ch = 0; ch < 8; ch++)
        kreg[0][kf][ch] = *(const bf16x8*)(kb + kf * 16 * H_ + ch * 32);
  }

  // Q tile -> LDS fragment-linearized: region = qf*8 + ch, 512 shorts each
#pragma unroll
  for (int i = 0; i < 16; i++) {
    int region = wave * 16 + i;
    int qf = region >> 3;
    int ch = region & 7;
    gl_lds16(Qb + (qcol0 + qf * 16 + l16) * H_ + ch * 32 + quad * 8,
             qbuf + region * 512);
  }
  __syncthreads();   // single drain; no barriers after this point

  const int quadA = quad >> 1;
  const int j0    = (quad & 1) * 4;

#pragma unroll
  for (int t = 0; t < 4; t++) {
    // prefetch K tile t+1 into the other register buffer (overlaps compute)
    if (t < 3) {
      const short* kb = Kb + ((ktg * 4 + t + 1) * 128 + wave * 32 + l16) * H_ + quad * 8;
#pragma unroll
      for (int kf = 0; kf < 2; kf++)
#pragma unroll
        for (int ch = 0; ch < 8; ch++)
          kreg[(t + 1) & 1][kf][ch] = *(const bf16x8*)(kb + kf * 16 * H_ + ch * 32);
    }

    f32x4 zero = {0.f, 0.f, 0.f, 0.f};
    f32x4 acc[2][8];
#pragma unroll
    for (int i = 0; i < 2; i++)
#pragma unroll
      for (int j = 0; j < 8; j++) acc[i][j] = zero;

#pragma unroll
    for (int ch = 0; ch < 8; ch++) {
#pragma unroll
      for (int qf = 0; qf < 8; qf++) {
        bf16x8 bq = *(const bf16x8*)(qbuf + (qf * 8 + ch) * 512 + lane * 8);
        acc[0][qf] = mfma16(kreg[t & 1][0][ch], bq, acc[0][qf]);
        acc[1][qf] = mfma16(kreg[t & 1][1][ch], bq, acc[1][qf]);
      }
    }

    const int kt    = ktg * 4 + t;
    const int krow0 = kt * 128 + wave * 32;
    const int kw    = krow0 >> 5;

    float rs[2][4] = {{0.f,0.f,0.f,0.f},{0.f,0.f,0.f,0.f}};
#pragma unroll
    for (int kf = 0; kf < 2; kf++) {
#pragma unroll
      for (int qf = 0; qf < 8; qf++) {
        bf16x4 pk;
#pragma unroll
        for (int r = 0; r < 4; r++) {
          float e = __expf(acc[kf][qf][r] * (1.0f / H_));
          rs[kf][r] += e;
          pk[r] = f2bf(e);
        }
        size_t tile = ((size_t)(b * 128 + qt * 8 + qf) << 6) + kw;
        *(bf16x4*)(Pf + (tile << 9) + ((2 * kf + quadA) * 16 + l16) * 8 + j0) = pk;
      }
    }

#pragma unroll
    for (int kf = 0; kf < 2; kf++) {
#pragma unroll
      for (int r = 0; r < 4; r++) {
        float v = rs[kf][r];
        v += __shfl_xor(v, 1, 64);
        v += __shfl_xor(v, 2, 64);
        v += __shfl_xor(v, 4, 64);
        v += __shfl_xor(v, 8, 64);
        if (l16 == 0)
          atomicAdd(&den[b * S_ + krow0 + kf * 16 + quad * 4 + r], v);
      }
    }
  }
}

// ---------------------------------------------------------------------------
// Kernel 3: VT[b][h][k] /= den[b][k]  (fold softmax denom into V).
// ---------------------------------------------------------------------------
__global__ __launch_bounds__(256) void vscale(
    short* __restrict__ VT, const float* __restrict__ den)
{
  int i = blockIdx.x * 256 + threadIdx.x;
  int b  = i >> 17;
  int k0 = (i & 511) << 2;
  float4 df = *(const float4*)(den + b * S_ + k0);
  bf16x4 v = *(bf16x4*)(VT + (size_t)i * 4);
  bf16x4 o;
  o[0] = f2bf(bf2f(v[0]) / df.x);
  o[1] = f2bf(bf2f(v[1]) / df.y);
  o[2] = f2bf(bf2f(v[2]) / df.z);
  o[3] = f2bf(bf2f(v[3]) / df.w);
  *(bf16x4*)(VT + (size_t)i * 4) = o;
}

// ---------------------------------------------------------------------------
// Kernel 4: out = Pf . Vs — LDS-staged GEMM, BK=128 (16 chunks, 32 barriers).
// r0 version (proven good inside the 185-186us composites).
// grid 512: bx = qt*16 + b*2 + hs (same-(b,hs) blocks -> same XCD -> V in L2).
// LDS 48 KiB: vbuf 32 regions (n,kw), abuf 16 regions (wave,kw).
// ---------------------------------------------------------------------------
__global__ __launch_bounds__(256) void pv(
    const short* __restrict__ Pf, const short* __restrict__ VTs,
    float* __restrict__ out)
{
  const int tid  = threadIdx.x;
  const int wave = tid >> 6;
  const int lane = tid & 63;
  const int quad = lane >> 4;
  const int l16  = lane & 15;
  const int bx = blockIdx.x;
  const int qt = bx >> 4;
  const int b  = (bx >> 1) & 7;
  const int hs = bx & 1;

  __shared__ short vbuf[32 * 512];   // 32 KiB
  __shared__ short abuf[16 * 512];   // 16 KiB

  const int qt16 = qt * 4 + wave;
  const short* VTb = VTs + (size_t)b * H_ * S_ + (size_t)(hs * 128) * S_;
  const size_t tilebase = ((size_t)(b * 128 + qt16) * 64) << 9;

  f32x4 zero = {0.f, 0.f, 0.f, 0.f};
  f32x4 acc[8];
#pragma unroll
  for (int i = 0; i < 8; i++) acc[i] = zero;

  for (int kc = 0; kc < S_; kc += 128) {
    // stage V: 32 regions, 8 per wave
#pragma unroll
    for (int i = 0; i < 8; i++) {
      int id = wave * 8 + i;
      int n  = id >> 2;
      int kw = id & 3;
      const short* g = VTb + (size_t)(n * 16 + l16) * S_ + kc + kw * 32 + quad * 8;
      gl_lds16(g, vbuf + id * 512);
    }
    // stage A: 4 regions per wave
#pragma unroll
    for (int kwi = 0; kwi < 4; kwi++) {
      const short* g = Pf + tilebase + (size_t)((kc >> 5) + kwi) * 512 + lane * 8;
      gl_lds16(g, abuf + (wave * 4 + kwi) * 512);
    }
    __syncthreads();
#pragma unroll
    for (int kw = 0; kw < 4; kw++) {
      bf16x8 a = *(const bf16x8*)(abuf + (wave * 4 + kw) * 512 + lane * 8);
#pragma unroll
      for (int n = 0; n < 8; n++) {
        bf16x8 vb = *(const bf16x8*)(vbuf + (n * 4 + kw) * 512 + lane * 8);
        acc[n] = mfma16(a, vb, acc[n]);
      }
    }
    __syncthreads();
  }

  const int q0 = qt16 * 16;
#pragma unroll
  for (int n = 0; n < 8; n++) {
    int col = hs * 128 + n * 16 + l16;
#pragma unroll
    for (int r = 0; r < 4; r++) {
      int q = q0 + quad * 4 + r;
      out[((size_t)b * S_ + q) * H_ + col] = acc[n][r];
    }
  }
}

extern "C" void kernel_launch(void* const* d_in, const int* in_sizes, int n_in,
                              void* d_out, int out_size, void* d_ws, size_t ws_size,
                              hipStream_t stream) {
  const float* x  = (const float*)d_in[0];
  const float* Wq = (const float*)d_in[1];
  const float* bq = (const float*)d_in[2];
  const float* Wk = (const float*)d_in[3];
  const float* bk = (const float*)d_in[4];
  const float* Wv = (const float*)d_in[5];
  const float* bv = (const float*)d_in[6];

  short* xb  = (short*)d_ws;                       // 8 MiB
  short* wqb = xb  + (size_t)BS_ * H_;             // 128 KiB each
  short* wkb = wqb + H_ * H_;
  short* wvb = wkb + H_ * H_;
  short* Qs  = wvb + H_ * H_;                      // 8 MiB
  short* Ks  = Qs  + (size_t)BS_ * H_;             // 8 MiB
  short* VT  = Ks  + (size_t)BS_ * H_;             // 8 MiB
  short* P   = VT  + (size_t)BS_ * H_;             // 64 MiB (frag-linearized)
  float* den = (float*)(P + (size_t)B_ * S_ * S_); // 64 KiB
  float* outp = (float*)d_out;

  cvt_bf16<<<1024, 256, 0, stream>>>(x, Wq, Wk, Wv, xb, wqb, wkb, wvb, den);
  qkv_proj<<<dim3(BS_ / 64, 3), 256, 0, stream>>>(xb, wqb, bq, wkb, bk, wvb, bv, Qs, Ks, VT);
  scores<<<512, 256, 0, stream>>>(Qs, Ks, P, den);
  vscale<<<4096, 256, 0, stream>>>(VT, den);
  pv<<<512, 256, 0, stream>>>(P, VT, outp);
}